// Round 3
// baseline (180.608 us; speedup 1.0000x reference)
//
#include <hip/hip_runtime.h>
#include <cstdint>
#include <cstddef>

#define HID    256
#define G4     1024          // 4*HID gates
#define KSTEPS 7
#define NBLK   4
#define TPB    1024
#define ZM     64
#define BATCH  32768

typedef float f32x4 __attribute__((ext_vector_type(4)));

// ---- workspace layout (floats) ----
// [0,256): barrier counters (6 counters at 32-uint stride), zeroed via hipMemsetAsync
// [256, 256+6*1024): gates buffers, one per LSTM step
// [256+6*1024, +896): projection table: [which(2)][m(7)][j(64)]
#define WS_GATES_F 256
#define WS_TAB_F   (256 + 6 * G4)

__device__ __forceinline__ void grid_barrier(unsigned* cnt) {
    __syncthreads();
    if (threadIdx.x == 0) {
        __hip_atomic_fetch_add(cnt, 1u, __ATOMIC_ACQ_REL, __HIP_MEMORY_SCOPE_AGENT);
        while (__hip_atomic_load(cnt, __ATOMIC_ACQUIRE, __HIP_MEMORY_SCOPE_AGENT) < (unsigned)NBLK) {
            __builtin_amdgcn_s_sleep(1);
        }
    }
    __syncthreads();
}

__device__ __forceinline__ float sigf(float x) { return 1.0f / (1.0f + expf(-x)); }

__global__ __launch_bounds__(TPB) void lstm_kernel(
    const float* __restrict__ zm1,
    const float* __restrict__ Wih, const float* __restrict__ Whh,
    const float* __restrict__ bih, const float* __restrict__ bhh,
    const float* __restrict__ Wloc, const float* __restrict__ bloc,
    const float* __restrict__ Wsc,  const float* __restrict__ bsc,
    float* __restrict__ ws)
{
    __shared__ float pz[KSTEPS][HID];   // p_z rows: [0]=zm1, [s]=h_s
    const int t    = threadIdx.x;
    const int b    = blockIdx.x;
    const int rloc = t >> 2;            // 0..255  (row within block)
    const int q    = t & 3;             // quarter of the 256-dot
    const int row  = b * (TPB / 4) + rloc;   // 0..1023 gate row

    unsigned* cnts = (unsigned*)ws;
    float* gates = ws + WS_GATES_F;
    float* tab   = ws + WS_TAB_F;

    if (t < HID) pz[0][t] = zm1[t];
    __syncthreads();

    const float bias = bih[row] + bhh[row];

    // ---- phase 0: load weights once into registers (strided float4 chunks for
    // cache-line-friendly access), fuse gates1 = W_ih . zm1 into the load ----
    float4 wsum[16];
    {
        const float4* a4 = (const float4*)(Wih + (size_t)row * HID);
        const float4* c4 = (const float4*)(Whh + (size_t)row * HID);
        const float4* x4 = (const float4*)(&pz[0][0]);
        float part = 0.f;
        #pragma unroll
        for (int kk = 0; kk < 16; ++kk) {
            const int idx = q + 4 * kk;
            float4 a = a4[idx];
            float4 c = c4[idx];
            float4 x = x4[idx];
            part += a.x * x.x + a.y * x.y + a.z * x.z + a.w * x.w;
            wsum[kk].x = a.x + c.x; wsum[kk].y = a.y + c.y;
            wsum[kk].z = a.z + c.z; wsum[kk].w = a.w + c.w;
        }
        part += __shfl_xor(part, 1);
        part += __shfl_xor(part, 2);
        if (q == 0)
            __hip_atomic_store(&gates[row], part + bias,
                               __ATOMIC_RELAXED, __HIP_MEMORY_SCOPE_AGENT);
    }

    // ---- sequential steps: barrier, h/c update (redundant per block), next gates ----
    float creg = 0.f;   // c-state lives in thread t (t < 256) registers
    #pragma unroll 1
    for (int s = 1; s <= KSTEPS - 1; ++s) {
        grid_barrier(&cnts[(s - 1) * 32]);
        if (t < HID) {
            const float* gs = gates + (size_t)(s - 1) * G4;
            float gi = __hip_atomic_load(&gs[t],           __ATOMIC_RELAXED, __HIP_MEMORY_SCOPE_AGENT);
            float gf = __hip_atomic_load(&gs[HID + t],     __ATOMIC_RELAXED, __HIP_MEMORY_SCOPE_AGENT);
            float gg = __hip_atomic_load(&gs[2 * HID + t], __ATOMIC_RELAXED, __HIP_MEMORY_SCOPE_AGENT);
            float go = __hip_atomic_load(&gs[3 * HID + t], __ATOMIC_RELAXED, __HIP_MEMORY_SCOPE_AGENT);
            creg = sigf(gf) * creg + sigf(gi) * tanhf(gg);
            pz[s][t] = sigf(go) * tanhf(creg);
        }
        __syncthreads();
        if (s == KSTEPS - 1) break;
        // gates for step s+1: x == h == pz[s], weights = W_ih + W_hh (in regs)
        const float4* h4 = (const float4*)(&pz[s][0]);
        float part = 0.f;
        #pragma unroll
        for (int kk = 0; kk < 16; ++kk) {
            const int idx = q + 4 * kk;
            float4 w = wsum[kk];
            float4 h = h4[idx];
            part += w.x * h.x + w.y * h.y + w.z * h.z + w.w * h.w;
        }
        part += __shfl_xor(part, 1);
        part += __shfl_xor(part, 2);
        if (q == 0)
            __hip_atomic_store(&gates[(size_t)s * G4 + row], part + bias,
                               __ATOMIC_RELAXED, __HIP_MEMORY_SCOPE_AGENT);
    }

    // ---- projections: 896 outputs = [which][m][j], 4 threads per output ----
    const int g    = b * TPB + t;    // 0..4095
    const int slot = g >> 2;         // 0..1023 ; g&3 == q
    if (slot < 2 * KSTEPS * ZM) {    // 896
        const int which = slot / (KSTEPS * ZM);
        const int r     = slot - which * (KSTEPS * ZM);
        const int m     = r >> 6;
        const int j     = r & 63;
        const float* W  = which ? Wsc : Wloc;
        const float  bb = which ? bsc[j] : bloc[j];
        const float4* w4 = (const float4*)(W + (size_t)j * HID);
        const float4* p4 = (const float4*)(&pz[m][0]);
        float acc = 0.f;
        #pragma unroll
        for (int kk = 0; kk < 16; ++kk) {
            const int idx = q + 4 * kk;
            float4 w = w4[idx];
            float4 p = p4[idx];
            acc += w.x * p.x + w.y * p.y + w.z * p.z + w.w * p.w;
        }
        acc += __shfl_xor(acc, 1);
        acc += __shfl_xor(acc, 2);
        if (q == 0) tab[slot] = acc + bb;   // slot == (which*7+m)*64 + j
    }
}

// ---- broadcast: 117.4 MB of pure coalesced nontemporal stores ----
// grid: 14 (which,m) groups * 128 chunks; block 256 threads; each thread holds
// one float4 table value and stores it 16 times (stride 4 KB, wave-contiguous).
__global__ __launch_bounds__(256) void bcast_kernel(
    const float* __restrict__ tab, f32x4* __restrict__ out)
{
    const int bid   = blockIdx.x;       // 0..1791
    const int wm    = bid >> 7;         // 0..13 = which*7 + m
    const int chunk = bid & 127;
    const f32x4* t4 = (const f32x4*)tab;
    const f32x4 v = t4[wm * 16 + (threadIdx.x & 15)];
    size_t base = (size_t)wm * (BATCH * ZM / 4) + (size_t)chunk * 4096 + threadIdx.x;
    #pragma unroll
    for (int k = 0; k < 16; ++k) {
        __builtin_nontemporal_store(v, &out[base + (size_t)k * 256]);
    }
}

extern "C" void kernel_launch(void* const* d_in, const int* in_sizes, int n_in,
                              void* d_out, int out_size, void* d_ws, size_t ws_size,
                              hipStream_t stream) {
    const float* zm1  = (const float*)d_in[0];
    const float* Wih  = (const float*)d_in[1];
    const float* Whh  = (const float*)d_in[2];
    const float* bih  = (const float*)d_in[3];
    const float* bhh  = (const float*)d_in[4];
    const float* Wloc = (const float*)d_in[5];
    const float* bloc = (const float*)d_in[6];
    const float* Wsc  = (const float*)d_in[7];
    const float* bsc  = (const float*)d_in[8];
    float* ws = (float*)d_ws;

    // zero the grid-barrier counters (ws is poisoned 0xAA before every launch)
    (void)hipMemsetAsync(d_ws, 0, 1024, stream);

    lstm_kernel<<<NBLK, TPB, 0, stream>>>(zm1, Wih, Whh, bih, bhh,
                                          Wloc, bloc, Wsc, bsc, ws);

    bcast_kernel<<<14 * 128, 256, 0, stream>>>(ws + WS_TAB_F, (f32x4*)d_out);
}

// Round 4
// 179.020 us; speedup vs baseline: 1.0089x; 1.0089x over previous
//
#include <hip/hip_runtime.h>
#include <cstdint>
#include <cstddef>

#define HID    256
#define G4     1024          // 4*HID gates
#define KSTEPS 7
#define NBLK   4
#define TPB    1024
#define ZM     64
#define BATCH  32768

typedef float f32x4 __attribute__((ext_vector_type(4)));

// ---- workspace layout (floats) ----
// [0,256): barrier counters (6 counters at 32-uint stride), zeroed via hipMemsetAsync
// [256, 256+6*1024): gates buffers, one per LSTM step
// [256+6*1024, +896): projection table: [which(2)][m(7)][j(64)]
#define WS_GATES_F 256
#define WS_TAB_F   (256 + 6 * G4)

__device__ __forceinline__ void grid_barrier(unsigned* cnt) {
    __syncthreads();
    if (threadIdx.x == 0) {
        __hip_atomic_fetch_add(cnt, 1u, __ATOMIC_ACQ_REL, __HIP_MEMORY_SCOPE_AGENT);
        while (__hip_atomic_load(cnt, __ATOMIC_ACQUIRE, __HIP_MEMORY_SCOPE_AGENT) < (unsigned)NBLK) {
            __builtin_amdgcn_s_sleep(1);
        }
    }
    __syncthreads();
}

// fast, NaN-free for |x| < 40 (our gate range is ~|x|<6)
__device__ __forceinline__ float sigf(float x)  { return 1.0f / (1.0f + __expf(-x)); }
__device__ __forceinline__ float tanhf_fast(float x) { return 1.0f - 2.0f / (__expf(2.0f * x) + 1.0f); }

__device__ __forceinline__ float dot4(f32x4 a, f32x4 b) {
    return a.x * b.x + a.y * b.y + a.z * b.z + a.w * b.w;
}

__global__ __launch_bounds__(TPB) void lstm_kernel(
    const float* __restrict__ zm1,
    const float* __restrict__ Wih, const float* __restrict__ Whh,
    const float* __restrict__ bih, const float* __restrict__ bhh,
    const float* __restrict__ Wloc, const float* __restrict__ bloc,
    const float* __restrict__ Wsc,  const float* __restrict__ bsc,
    float* __restrict__ ws)
{
    __shared__ float pz[KSTEPS][HID];   // p_z rows: [0]=zm1, [s]=h_s
    __shared__ float act[G4];           // per-step gate activations
    const int t    = threadIdx.x;
    const int b    = blockIdx.x;
    const int rloc = t >> 2;            // 0..255  (row within block)
    const int q    = t & 3;             // quarter of the 256-dot
    const int row  = b * (TPB / 4) + rloc;   // 0..1023 gate row

    unsigned* cnts = (unsigned*)ws;
    float* gates = ws + WS_GATES_F;
    float* tab   = ws + WS_TAB_F;

    if (t < HID) pz[0][t] = zm1[t];
    __syncthreads();

    const float bias = bih[row] + bhh[row];

    // ---- phase 0: two-pass weight load to cap live VGPRs (~80 peak).
    // pass A: wsum = Wih row, fused with gates1 = Wih . zm1 (h0 == 0).
    // pass B: wsum += Whh row.
    f32x4 wsum[16];
    {
        const f32x4* a4 = (const f32x4*)(Wih + (size_t)row * HID);
        const f32x4* x4 = (const f32x4*)(&pz[0][0]);
        float part = 0.f;
        #pragma unroll
        for (int kk = 0; kk < 16; ++kk) {
            const int idx = q + 4 * kk;
            f32x4 a = a4[idx];
            wsum[kk] = a;
            part += dot4(a, x4[idx]);
        }
        const f32x4* c4 = (const f32x4*)(Whh + (size_t)row * HID);
        #pragma unroll
        for (int kk = 0; kk < 16; ++kk) {
            wsum[kk] += c4[q + 4 * kk];
        }
        part += __shfl_xor(part, 1);
        part += __shfl_xor(part, 2);
        if (q == 0)
            __hip_atomic_store(&gates[row], part + bias,
                               __ATOMIC_RELAXED, __HIP_MEMORY_SCOPE_AGENT);
    }

    // ---- sequential steps: barrier, activation (all 1024 threads), h/c update,
    // next gates. Every block redundantly updates h/c (deterministic f32). ----
    float creg = 0.f;   // c-state lives in thread t (t < 256) registers
    #pragma unroll 1
    for (int s = 1; s <= KSTEPS - 1; ++s) {
        grid_barrier(&cnts[(s - 1) * 32]);
        // coalesced 1024-wide gate load; one transcendental per thread
        {
            const float* gs = gates + (size_t)(s - 1) * G4;
            float g = __hip_atomic_load(&gs[t], __ATOMIC_RELAXED, __HIP_MEMORY_SCOPE_AGENT);
            // slots: [0,256)=i sig, [256,512)=f sig, [512,768)=g tanh, [768,1024)=o sig
            act[t] = (t >= 512 && t < 768) ? tanhf_fast(g) : sigf(g);
        }
        __syncthreads();
        if (t < HID) {
            creg = act[HID + t] * creg + act[t] * act[2 * HID + t];
            pz[s][t] = act[3 * HID + t] * tanhf_fast(creg);
        }
        __syncthreads();
        if (s == KSTEPS - 1) break;
        // gates for step s+1: x == h == pz[s], weights = W_ih + W_hh (in regs)
        const f32x4* h4 = (const f32x4*)(&pz[s][0]);
        float part = 0.f;
        #pragma unroll
        for (int kk = 0; kk < 16; ++kk) {
            part += dot4(wsum[kk], h4[q + 4 * kk]);
        }
        part += __shfl_xor(part, 1);
        part += __shfl_xor(part, 2);
        if (q == 0)
            __hip_atomic_store(&gates[(size_t)s * G4 + row], part + bias,
                               __ATOMIC_RELAXED, __HIP_MEMORY_SCOPE_AGENT);
    }

    // ---- projections: 896 outputs = [which][m][j], 4 threads per output ----
    const int g    = b * TPB + t;    // 0..4095
    const int slot = g >> 2;         // 0..1023 ; g&3 == q
    if (slot < 2 * KSTEPS * ZM) {    // 896
        const int which = slot / (KSTEPS * ZM);
        const int r     = slot - which * (KSTEPS * ZM);
        const int m     = r >> 6;
        const int j     = r & 63;
        const float* W  = which ? Wsc : Wloc;
        const float  bb = which ? bsc[j] : bloc[j];
        const f32x4* w4 = (const f32x4*)(W + (size_t)j * HID);
        const f32x4* p4 = (const f32x4*)(&pz[m][0]);
        float acc = 0.f;
        #pragma unroll
        for (int kk = 0; kk < 16; ++kk) {
            const int idx = q + 4 * kk;
            acc += dot4(w4[idx], p4[idx]);
        }
        acc += __shfl_xor(acc, 1);
        acc += __shfl_xor(acc, 2);
        if (q == 0) tab[slot] = acc + bb;   // slot == (which*7+m)*64 + j
    }
}

// ---- broadcast: 117.4 MB of pure coalesced nontemporal stores ----
// grid: 14 (which,m) groups * 128 chunks; block 256 threads; each thread holds
// one float4 table value and stores it 16 times (stride 4 KB, wave-contiguous).
__global__ __launch_bounds__(256) void bcast_kernel(
    const float* __restrict__ tab, f32x4* __restrict__ out)
{
    const int bid   = blockIdx.x;       // 0..1791
    const int wm    = bid >> 7;         // 0..13 = which*7 + m
    const int chunk = bid & 127;
    const f32x4* t4 = (const f32x4*)tab;
    const f32x4 v = t4[wm * 16 + (threadIdx.x & 15)];
    size_t base = (size_t)wm * (BATCH * ZM / 4) + (size_t)chunk * 4096 + threadIdx.x;
    #pragma unroll
    for (int k = 0; k < 16; ++k) {
        __builtin_nontemporal_store(v, &out[base + (size_t)k * 256]);
    }
}

extern "C" void kernel_launch(void* const* d_in, const int* in_sizes, int n_in,
                              void* d_out, int out_size, void* d_ws, size_t ws_size,
                              hipStream_t stream) {
    const float* zm1  = (const float*)d_in[0];
    const float* Wih  = (const float*)d_in[1];
    const float* Whh  = (const float*)d_in[2];
    const float* bih  = (const float*)d_in[3];
    const float* bhh  = (const float*)d_in[4];
    const float* Wloc = (const float*)d_in[5];
    const float* bloc = (const float*)d_in[6];
    const float* Wsc  = (const float*)d_in[7];
    const float* bsc  = (const float*)d_in[8];
    float* ws = (float*)d_ws;

    // zero the grid-barrier counters (ws is poisoned 0xAA before every launch)
    (void)hipMemsetAsync(d_ws, 0, 1024, stream);

    lstm_kernel<<<NBLK, TPB, 0, stream>>>(zm1, Wih, Whh, bih, bhh,
                                          Wloc, bloc, Wsc, bsc, ws);

    bcast_kernel<<<14 * 128, 256, 0, stream>>>(ws + WS_TAB_F, (f32x4*)d_out);
}

// Round 5
// 164.958 us; speedup vs baseline: 1.0949x; 1.0852x over previous
//
#include <hip/hip_runtime.h>
#include <cstdint>
#include <cstddef>

#define HID    256
#define NROW   1024          // 4*HID gate rows
#define KSTEPS 7
#define ZM     64
#define BATCH  32768

typedef float f32x4 __attribute__((ext_vector_type(4)));

// ---- workspace layout (float offsets). No barrier counters, no memset. ----
#define WS_GATES 0                         // 6 buffers of NROW (gates for h_1..h_6)
#define WS_C     (6 * NROW)                // 7 x 256 c-state chain
#define WS_PZ    (6 * NROW + 7 * HID)      // 7 x 256 p_z rows
#define WS_TAB   (6 * NROW + 14 * HID)     // 896 projection table [which][m][j]
#define WS_WSUM  (6 * NROW + 14 * HID + 896)  // 1024 x 256 = W_ih + W_hh

// fast, NaN-free for the gate range we see (|x| < ~6)
__device__ __forceinline__ float sigf(float x)       { return 1.0f / (1.0f + __expf(-x)); }
__device__ __forceinline__ float tanhf_fast(float x) { return 1.0f - 2.0f / (__expf(2.0f * x) + 1.0f); }

__device__ __forceinline__ float dot4(f32x4 a, f32x4 b) {
    return a.x * b.x + a.y * b.y + a.z * b.z + a.w * b.w;
}

// ---- init: Wsum = Wih + Whh into ws; gates0 = Wih . zm1 + bias; pz[0], c[0] ----
__global__ __launch_bounds__(256) void init_kernel(
    const float* __restrict__ zm1,
    const float* __restrict__ Wih, const float* __restrict__ Whh,
    const float* __restrict__ bih, const float* __restrict__ bhh,
    float* __restrict__ ws)
{
    const int t = threadIdx.x, b = blockIdx.x;
    f32x4*       wsum4 = (f32x4*)(ws + WS_WSUM);
    const f32x4* a4    = (const f32x4*)Wih;
    const f32x4* c4    = (const f32x4*)Whh;
    const int id = b * 256 + t;          // 0..65535 f32x4 elements of the 1 MB matrix
    wsum4[id] = a4[id] + c4[id];

    if (b == 0) {                        // pz[0] = zm1 ; c[0] = 0
        ws[WS_PZ + t] = zm1[t];
        ws[WS_C + t]  = 0.0f;
    }
    if (b < 64) {                        // gates0: rows 16b .. 16b+16 (h0 == 0)
        const int row = b * 16 + (t >> 4);
        const int l16 = t & 15;
        const f32x4* w4 = (const f32x4*)(Wih + (size_t)row * HID);
        const f32x4* x4 = (const f32x4*)zm1;
        float part = 0.f;
        #pragma unroll
        for (int kk = 0; kk < 4; ++kk) part += dot4(w4[l16 * 4 + kk], x4[l16 * 4 + kk]);
        part += __shfl_xor(part, 1);
        part += __shfl_xor(part, 2);
        part += __shfl_xor(part, 4);
        part += __shfl_xor(part, 8);
        if (l16 == 0) ws[WS_GATES + row] = part + bih[row] + bhh[row];
    }
}

// ---- step s (1..5): h_s from gates[s-1] (redundant per block), gates[s] = Wsum.h ----
__global__ __launch_bounds__(256) void step_kernel(
    const float* __restrict__ bih, const float* __restrict__ bhh,
    float* __restrict__ ws, int s)
{
    __shared__ float hsh[HID];
    const int t = threadIdx.x, b = blockIdx.x;
    {
        const float* gp = ws + WS_GATES + (size_t)(s - 1) * NROW;
        float gi = gp[t], gf = gp[HID + t], gg = gp[2 * HID + t], go = gp[3 * HID + t];
        float cp = ws[WS_C + (size_t)(s - 1) * HID + t];
        float cn = sigf(gf) * cp + sigf(gi) * tanhf_fast(gg);
        float h  = sigf(go) * tanhf_fast(cn);
        ws[WS_C + (size_t)s * HID + t] = cn;            // identical dup writes: benign
        if (b == 0) ws[WS_PZ + (size_t)s * HID + t] = h;
        hsh[t] = h;
    }
    __syncthreads();
    const int row = b * 16 + (t >> 4);
    const int l16 = t & 15;
    const f32x4* w4 = (const f32x4*)(ws + WS_WSUM + (size_t)row * HID);
    const f32x4* h4 = (const f32x4*)hsh;
    float part = 0.f;
    #pragma unroll
    for (int kk = 0; kk < 4; ++kk) part += dot4(w4[l16 * 4 + kk], h4[l16 * 4 + kk]);
    part += __shfl_xor(part, 1);
    part += __shfl_xor(part, 2);
    part += __shfl_xor(part, 4);
    part += __shfl_xor(part, 8);
    if (l16 == 0) ws[WS_GATES + (size_t)s * NROW + row] = part + bih[row] + bhh[row];
}

// ---- final: h6 from gates[5]; projections into tab (14 blocks = [which][m]) ----
__global__ __launch_bounds__(256) void final_kernel(
    const float* __restrict__ Wloc, const float* __restrict__ bloc,
    const float* __restrict__ Wsc,  const float* __restrict__ bsc,
    float* __restrict__ ws)
{
    __shared__ float hsh[HID];
    const int t = threadIdx.x, b = blockIdx.x;
    {
        const float* gp = ws + WS_GATES + (size_t)5 * NROW;
        float gi = gp[t], gf = gp[HID + t], gg = gp[2 * HID + t], go = gp[3 * HID + t];
        float cp = ws[WS_C + (size_t)5 * HID + t];
        float cn = sigf(gf) * cp + sigf(gi) * tanhf_fast(gg);
        hsh[t] = sigf(go) * tanhf_fast(cn);             // h6 == pz[6]
    }
    __syncthreads();
    const int wm    = b;                 // 0..13 = which*7 + m
    const int which = wm / KSTEPS;
    const int m     = wm % KSTEPS;
    const int j     = t >> 2;            // 0..63
    const int q     = t & 3;
    const float* W  = which ? Wsc : Wloc;
    const float  bb = which ? bsc[j] : bloc[j];
    const f32x4* w4 = (const f32x4*)(W + (size_t)j * HID);
    const f32x4* p4 = (m == 6) ? (const f32x4*)hsh
                               : (const f32x4*)(ws + WS_PZ + (size_t)m * HID);
    float acc = 0.f;
    #pragma unroll
    for (int kk = 0; kk < 16; ++kk) acc += dot4(w4[q * 16 + kk], p4[q * 16 + kk]);
    acc += __shfl_xor(acc, 1);
    acc += __shfl_xor(acc, 2);
    if (q == 0) ws[WS_TAB + wm * ZM + j] = acc + bb;
}

// ---- broadcast: 117.4 MB of pure coalesced nontemporal stores ----
__global__ __launch_bounds__(256) void bcast_kernel(
    const float* __restrict__ tab, f32x4* __restrict__ out)
{
    const int bid   = blockIdx.x;       // 0..1791
    const int wm    = bid >> 7;         // 0..13
    const int chunk = bid & 127;
    const f32x4* t4 = (const f32x4*)tab;
    const f32x4 v = t4[wm * 16 + (threadIdx.x & 15)];
    size_t base = (size_t)wm * (BATCH * ZM / 4) + (size_t)chunk * 4096 + threadIdx.x;
    #pragma unroll
    for (int k = 0; k < 16; ++k) {
        __builtin_nontemporal_store(v, &out[base + (size_t)k * 256]);
    }
}

extern "C" void kernel_launch(void* const* d_in, const int* in_sizes, int n_in,
                              void* d_out, int out_size, void* d_ws, size_t ws_size,
                              hipStream_t stream) {
    const float* zm1  = (const float*)d_in[0];
    const float* Wih  = (const float*)d_in[1];
    const float* Whh  = (const float*)d_in[2];
    const float* bih  = (const float*)d_in[3];
    const float* bhh  = (const float*)d_in[4];
    const float* Wloc = (const float*)d_in[5];
    const float* bloc = (const float*)d_in[6];
    const float* Wsc  = (const float*)d_in[7];
    const float* bsc  = (const float*)d_in[8];
    float* ws = (float*)d_ws;

    init_kernel<<<256, 256, 0, stream>>>(zm1, Wih, Whh, bih, bhh, ws);
    for (int s = 1; s <= 5; ++s)
        step_kernel<<<64, 256, 0, stream>>>(bih, bhh, ws, s);
    final_kernel<<<14, 256, 0, stream>>>(Wloc, bloc, Wsc, bsc, ws);
    bcast_kernel<<<14 * 128, 256, 0, stream>>>(ws + WS_TAB, (f32x4*)d_out);
}